// Round 12
// baseline (301.843 us; speedup 1.0000x reference)
//
#include <hip/hip_runtime.h>
#include <hip/hip_bf16.h>

#define BB   4096
#define DD   128
#define NII  50000

typedef __attribute__((ext_vector_type(8))) short  bf8_t;   // 8 bf16 in 4 VGPRs
typedef __attribute__((ext_vector_type(4))) float  f4_t;
typedef __attribute__((ext_vector_type(4))) unsigned short us4_t;
typedef __attribute__((ext_vector_type(4))) float  fl4_t;

static __device__ __forceinline__ unsigned short f2bf(float f) {
    unsigned u = __float_as_uint(f);
    u += 0x7fffu + ((u >> 16) & 1u);       // round-to-nearest-even
    return (unsigned short)(u >> 16);
}

static __device__ __forceinline__ void gload_lds16(const void* g, void* lds) {
    __builtin_amdgcn_global_load_lds(
        (const __attribute__((address_space(1))) void*)g,
        (__attribute__((address_space(3))) void*)lds, 16, 0, 0);
}

// ---------------- K1: gather + LN1 + t = nf @ send_W, s2 = t . a2 ----------------
__global__ __launch_bounds__(128) void k1_embed_send(
    const int* __restrict__ uidx, const float* __restrict__ utab,
    const float* __restrict__ g1, const float* __restrict__ b1,
    const float* __restrict__ sendW, const float* __restrict__ senda,
    float* __restrict__ t_out, float* __restrict__ s2_out)
{
    __shared__ float sb[128];
    __shared__ float nf[128];
    const int row = blockIdx.x;
    const int tid = threadIdx.x;
    const long urow = uidx[row];
    const float x = utab[urow * 128 + tid];

    sb[tid] = x; __syncthreads();
    for (int s = 64; s > 0; s >>= 1) { if (tid < s) sb[tid] += sb[tid + s]; __syncthreads(); }
    const float mean = sb[0] * (1.0f / 128.0f); __syncthreads();
    const float dv = x - mean;
    sb[tid] = dv * dv; __syncthreads();
    for (int s = 64; s > 0; s >>= 1) { if (tid < s) sb[tid] += sb[tid + s]; __syncthreads(); }
    const float var = sb[0] * (1.0f / 128.0f);
    const float rs = rsqrtf(var + 1e-5f);
    nf[tid] = dv * rs * g1[tid] + b1[tid];
    __syncthreads();

    float acc = 0.f;
    #pragma unroll 8
    for (int d = 0; d < 128; ++d) acc += nf[d] * sendW[d * 128 + tid];
    t_out[row * 128 + tid] = acc;

    const float p = acc * senda[128 + tid];   // a2 = send_a[128:]
    __syncthreads();
    sb[tid] = p; __syncthreads();
    for (int s = 64; s > 0; s >>= 1) { if (tid < s) sb[tid] += sb[tid + s]; __syncthreads(); }
    if (tid == 0) s2_out[row] = sb[0];
}

// ---------------- K2b: stats (recomputed per block) + weighted column partial sums ----------------
__global__ __launch_bounds__(256) void k2b_colsum(
    const float* __restrict__ t, const float* __restrict__ s2,
    float* __restrict__ partial)
{
    __shared__ float ew[128];
    __shared__ float sb[256];
    const int tid = threadIdx.x;

    float m = -1e30f;
    for (int i = tid; i < BB; i += 256) m = fmaxf(m, s2[i]);
    sb[tid] = m; __syncthreads();
    for (int s = 128; s > 0; s >>= 1) { if (tid < s) sb[tid] = fmaxf(sb[tid], sb[tid + s]); __syncthreads(); }
    m = sb[0]; __syncthreads();

    const int rbase = blockIdx.x * 128;
    if (tid < 128) ew[tid] = __expf(s2[rbase + tid] - m);
    __syncthreads();
    const int col = tid & 127, half = tid >> 7;
    float acc = 0.f;
    for (int j = half; j < 128; j += 2)
        acc += ew[j] * t[(rbase + j) * 128 + col];
    sb[tid] = acc; __syncthreads();
    if (tid < 128) partial[blockIdx.x * 128 + tid] = sb[tid] + sb[tid + 128];
}

// ---------------- K2c: stats + sent -> ap -> LN2 -> t2 -> r = sin(t2) ----------------
__global__ __launch_bounds__(128) void k2c_finish(
    const float* __restrict__ partial, const float* __restrict__ s2,
    const float* __restrict__ anchors, const float* __restrict__ g2,
    const float* __restrict__ b2, const float* __restrict__ recvW,
    float* __restrict__ r_out)
{
    __shared__ float sent[128];
    __shared__ float na_s[128];
    __shared__ float sb[128];
    const int tid = threadIdx.x;

    float m = -1e30f;
    for (int i = tid; i < BB; i += 128) m = fmaxf(m, s2[i]);
    sb[tid] = m; __syncthreads();
    for (int s = 64; s > 0; s >>= 1) { if (tid < s) sb[tid] = fmaxf(sb[tid], sb[tid + s]); __syncthreads(); }
    m = sb[0]; __syncthreads();
    float sum = 0.f;
    for (int i = tid; i < BB; i += 128) sum += __expf(s2[i] - m);
    sb[tid] = sum; __syncthreads();
    for (int s = 64; s > 0; s >>= 1) { if (tid < s) sb[tid] += sb[tid + s]; __syncthreads(); }
    const float S = sb[0]; __syncthreads();

    float acc = 0.f;
    for (int b = 0; b < 32; ++b) acc += partial[b * 128 + tid];
    sent[tid] = acc / S;
    __syncthreads();
    float ap = 0.f;
    for (int c = 0; c < 128; ++c) ap += sent[c] * anchors[tid * 128 + c];
    sb[tid] = ap; __syncthreads();
    for (int s = 64; s > 0; s >>= 1) { if (tid < s) sb[tid] += sb[tid + s]; __syncthreads(); }
    const float mean = sb[0] * (1.0f / 128.0f); __syncthreads();
    const float dv = ap - mean;
    sb[tid] = dv * dv; __syncthreads();
    for (int s = 64; s > 0; s >>= 1) { if (tid < s) sb[tid] += sb[tid + s]; __syncthreads(); }
    const float var = sb[0] * (1.0f / 128.0f);
    const float rs = rsqrtf(var + 1e-5f);
    na_s[tid] = dv * rs * g2[tid] + b2[tid];
    __syncthreads();
    float t2 = 0.f;
    for (int k = 0; k < 128; ++k) t2 += na_s[k] * recvW[k * 128 + tid];
    r_out[tid] = sinf(t2);     // rec row == t2 row (uniform softmax over identical rows)
}

// ---------------- K3: ue = u + r (f32 + bf16 copy), pos gather ----------------
__global__ __launch_bounds__(256) void k3_ue_pos(
    const int* __restrict__ uidx, const float* __restrict__ utab,
    const int* __restrict__ pidx, const float* __restrict__ itab,
    const float* __restrict__ r, float* __restrict__ ue_out,
    float* __restrict__ pos_out, unsigned short* __restrict__ uebf)
{
    const int gid = blockIdx.x * 256 + threadIdx.x;    // 0 .. 524287
    const int i = gid >> 7, d = gid & 127;
    const float rv = r[d];
    const float u = utab[(long)uidx[i] * 128 + d];
    const float ue = u + rv;
    ue_out[gid] = ue;
    uebf[gid] = f2bf(ue);
    pos_out[gid] = itab[(long)pidx[i] * 128 + d];
}

// ---------------- K3b: item_table -> bf16 ----------------
__global__ __launch_bounds__(256) void k3b_cvt_item(
    const float* __restrict__ itab, unsigned short* __restrict__ ibf)
{
    const int gid = blockIdx.x * 256 + threadIdx.x;    // 0 .. 1,599,999 (x4 elems)
    const fl4_t v = *(const fl4_t*)(itab + (long)gid * 4);
    us4_t o;
    o.x = f2bf(v.x); o.y = f2bf(v.y); o.z = f2bf(v.z); o.w = f2bf(v.w);
    *(us4_t*)(ibf + (long)gid * 4) = o;
}

// ---------------- K4 v12: preds = ue @ item^T  (256x256 tile, B-only LDS, 2 blocks/CU) ----------------
// v10's tile/wave layout, but only B staged in LDS (64 KB) -> 2 blocks/CU, so one block's
// staging hides under the other's compute+stores (kills the ~5 us/generation bubble that
// capped v10). A fragments read per-k-step directly from global (1 MB pool, L2-resident),
// 1-deep pipelined (a_cur/a_nxt) to bound VGPR. Staging ratio 0.25.
__global__ __launch_bounds__(512, 2) void k4_gemm(
    const unsigned short* __restrict__ uebf,
    const unsigned short* __restrict__ ibf,
    float* __restrict__ preds)
{
    __shared__ unsigned short lB[256 * 128];   // 64 KB: 256 N-cols x 256 B

    const int tid = threadIdx.x;
    const int wave = tid >> 6, lane = tid & 63;
    const int l15 = lane & 15, kg = lane >> 4;       // kg 0..3
    const int col0 = blockIdx.x * 256;               // N tile (fastest-varying)
    const int row0 = blockIdx.y * 256;               // M tile

    // ---- stage B (64 KB): 8 instrs x 8 KB (512 thr x 16 B), XOR-swizzled source
    #pragma unroll
    for (int i = 0; i < 8; ++i) {
        const int o  = (i * 512 + tid) * 16;
        const int r  = o >> 8;                       // tile-local col-row, 0..255
        const int ch = (o >> 4) & 15;
        const int sw = ch ^ (r & 15);
        const int bc = (col0 + r) < NII ? (col0 + r) : (NII - 1);
        gload_lds16(ibf + (size_t)bc * 128 + sw * 8,
                    (char*)lB + i * 8192 + wave * 1024);
    }

    const int wr = wave >> 2, wcn = wave & 3;        // 2x4 wave grid: wave tile 128M x 64N

    f4_t acc[8][4];
    #pragma unroll
    for (int m = 0; m < 8; ++m)
        #pragma unroll
        for (int n = 0; n < 4; ++n) acc[m][n] = (f4_t){0.f, 0.f, 0.f, 0.f};

    // A base for this lane: row = row0 + wr*128 + m*16 + l15, chunk kg (+4*kk)
    const unsigned short* abase =
        uebf + (size_t)(row0 + wr * 128 + l15) * 128 + kg * 8;

    // prefetch a(kk=0) while B-stage is in flight
    bf8_t a_cur[8], a_nxt[8];
    #pragma unroll
    for (int m = 0; m < 8; ++m)
        a_cur[m] = *(const bf8_t*)(abase + (size_t)m * 16 * 128);

    __syncthreads();                                 // B landed (drains stage vmcnt)

    #pragma unroll
    for (int kk = 0; kk < 4; ++kk) {                 // K step of 32
        if (kk < 3) {
            #pragma unroll
            for (int m = 0; m < 8; ++m)
                a_nxt[m] = *(const bf8_t*)(abase + (size_t)m * 16 * 128 + (kk + 1) * 32);
        }
        const int c = kk * 4 + kg;
        bf8_t b[4];
        #pragma unroll
        for (int n = 0; n < 4; ++n) {
            const int r = wcn * 64 + n * 16 + l15;
            b[n] = *(const bf8_t*)((const char*)lB + r * 256 + (c ^ (r & 15)) * 16);
        }
        #pragma unroll
        for (int m = 0; m < 8; ++m)
            #pragma unroll
            for (int n = 0; n < 4; ++n)
                acc[m][n] = __builtin_amdgcn_mfma_f32_16x16x32_bf16(b[n], a_cur[m], acc[m][n], 0, 0, 0);
        #pragma unroll
        for (int m = 0; m < 8; ++m) a_cur[m] = a_nxt[m];
    }

    // ---- direct store (swapped operands): lane (kg,l15) holds
    //      preds[row0+wr*128+m*16+l15][col0+wcn*64+n*16+kg*4 .. +3]
    #pragma unroll
    for (int m = 0; m < 8; ++m) {
        const long grow = row0 + wr * 128 + m * 16 + l15;
        #pragma unroll
        for (int n = 0; n < 4; ++n) {
            const int gcol = col0 + wcn * 64 + n * 16 + kg * 4;
            if (gcol < NII)                          // NII%4==0 -> gcol<NII => gcol+3<NII
                *(fl4_t*)(preds + grow * NII + gcol) = acc[m][n];
        }
    }
}

extern "C" void kernel_launch(void* const* d_in, const int* in_sizes, int n_in,
                              void* d_out, int out_size, void* d_ws, size_t ws_size,
                              hipStream_t stream) {
    const int*   uidx   = (const int*)  d_in[0];
    const int*   pidx   = (const int*)  d_in[1];
    const float* utab   = (const float*)d_in[2];
    const float* itab   = (const float*)d_in[3];
    const float* g1     = (const float*)d_in[4];
    const float* b1     = (const float*)d_in[5];
    const float* sendW  = (const float*)d_in[6];
    const float* senda  = (const float*)d_in[7];
    const float* anchors= (const float*)d_in[8];
    const float* g2     = (const float*)d_in[9];
    const float* b2     = (const float*)d_in[10];
    const float* recvW  = (const float*)d_in[11];
    // d_in[12] (recv_a) provably unused: second fca's softmax weights are exactly uniform.

    char* ws = (char*)d_ws;
    float* t_ws    = (float*)(ws + 0);              // 4096*128*4 = 2,097,152
    float* s2_ws   = (float*)(ws + 2097152);        // 16,384
    float* part_ws = (float*)(ws + 2113600);        // 32*128*4 = 16,384
    float* r_ws    = (float*)(ws + 2129984);        // 512
    unsigned short* uebf = (unsigned short*)(ws + 2130496);   // 1,048,576
    unsigned short* ibf  = (unsigned short*)(ws + 3179072);   // 12,800,000 -> ends ~15.98 MB

    float* preds   = (float*)d_out;
    float* ue_out  = preds + (long)BB * NII;
    float* pos_out = ue_out + BB * DD;

    k3b_cvt_item<<<6250, 256, 0, stream>>>(itab, ibf);
    k1_embed_send<<<4096, 128, 0, stream>>>(uidx, utab, g1, b1, sendW, senda, t_ws, s2_ws);
    k2b_colsum<<<32, 256, 0, stream>>>(t_ws, s2_ws, part_ws);
    k2c_finish<<<1, 128, 0, stream>>>(part_ws, s2_ws, anchors, g2, b2, recvW, r_ws);
    k3_ue_pos<<<2048, 256, 0, stream>>>(uidx, utab, pidx, itab, r_ws, ue_out, pos_out, uebf);
    k4_gemm<<<dim3(196, 16, 1), 512, 0, stream>>>(uebf, ibf, preds);
}

// Round 13
// 237.988 us; speedup vs baseline: 1.2683x; 1.2683x over previous
//
#include <hip/hip_runtime.h>
#include <hip/hip_bf16.h>

#define BB   4096
#define DD   128
#define NII  50000

typedef __attribute__((ext_vector_type(8))) short  bf8_t;   // 8 bf16 in 4 VGPRs
typedef __attribute__((ext_vector_type(4))) float  f4_t;
typedef __attribute__((ext_vector_type(4))) unsigned short us4_t;
typedef __attribute__((ext_vector_type(4))) float  fl4_t;

static __device__ __forceinline__ unsigned short f2bf(float f) {
    unsigned u = __float_as_uint(f);
    u += 0x7fffu + ((u >> 16) & 1u);       // round-to-nearest-even
    return (unsigned short)(u >> 16);
}

static __device__ __forceinline__ void gload_lds16(const void* g, void* lds) {
    __builtin_amdgcn_global_load_lds(
        (const __attribute__((address_space(1))) void*)g,
        (__attribute__((address_space(3))) void*)lds, 16, 0, 0);
}

// ---------------- KA: fused {k1 gather+LN1+send (blocks 0..4095)} ∥ {item->bf16 (rest)} ----------------
__global__ __launch_bounds__(128) void kA_embed_cvt(
    const int* __restrict__ uidx, const float* __restrict__ utab,
    const float* __restrict__ g1, const float* __restrict__ b1,
    const float* __restrict__ sendW, const float* __restrict__ senda,
    const float* __restrict__ itab,
    float* __restrict__ t_out, float* __restrict__ s2_out,
    unsigned short* __restrict__ ibf)
{
    const int tid = threadIdx.x;
    if (blockIdx.x >= BB) {
        // ---- item_table -> bf16: 6250 blocks x 128 thr x 8 elems = 6.4e6
        const long gid = ((long)(blockIdx.x - BB) * 128 + tid) * 2;  // float4-pairs
        #pragma unroll
        for (int h = 0; h < 2; ++h) {
            const fl4_t v = *(const fl4_t*)(itab + (gid + h) * 4);
            us4_t o;
            o.x = f2bf(v.x); o.y = f2bf(v.y); o.z = f2bf(v.z); o.w = f2bf(v.w);
            *(us4_t*)(ibf + (gid + h) * 4) = o;
        }
        return;
    }

    __shared__ float sb[128];
    __shared__ float nf[128];
    const int row = blockIdx.x;
    const long urow = uidx[row];
    const float x = utab[urow * 128 + tid];

    sb[tid] = x; __syncthreads();
    for (int s = 64; s > 0; s >>= 1) { if (tid < s) sb[tid] += sb[tid + s]; __syncthreads(); }
    const float mean = sb[0] * (1.0f / 128.0f); __syncthreads();
    const float dv = x - mean;
    sb[tid] = dv * dv; __syncthreads();
    for (int s = 64; s > 0; s >>= 1) { if (tid < s) sb[tid] += sb[tid + s]; __syncthreads(); }
    const float var = sb[0] * (1.0f / 128.0f);
    const float rs = rsqrtf(var + 1e-5f);
    nf[tid] = dv * rs * g1[tid] + b1[tid];
    __syncthreads();

    float acc = 0.f;
    #pragma unroll 8
    for (int d = 0; d < 128; ++d) acc += nf[d] * sendW[d * 128 + tid];
    t_out[row * 128 + tid] = acc;

    const float p = acc * senda[128 + tid];   // a2 = send_a[128:]
    __syncthreads();
    sb[tid] = p; __syncthreads();
    for (int s = 64; s > 0; s >>= 1) { if (tid < s) sb[tid] += sb[tid + s]; __syncthreads(); }
    if (tid == 0) s2_out[row] = sb[0];
}

// ---------------- K2b: stats (recomputed per block) + weighted column partial sums ----------------
__global__ __launch_bounds__(256) void k2b_colsum(
    const float* __restrict__ t, const float* __restrict__ s2,
    float* __restrict__ partial)
{
    __shared__ float ew[128];
    __shared__ float sb[256];
    const int tid = threadIdx.x;

    float m = -1e30f;
    for (int i = tid; i < BB; i += 256) m = fmaxf(m, s2[i]);
    sb[tid] = m; __syncthreads();
    for (int s = 128; s > 0; s >>= 1) { if (tid < s) sb[tid] = fmaxf(sb[tid], sb[tid + s]); __syncthreads(); }
    m = sb[0]; __syncthreads();

    const int rbase = blockIdx.x * 128;
    if (tid < 128) ew[tid] = __expf(s2[rbase + tid] - m);
    __syncthreads();
    const int col = tid & 127, half = tid >> 7;
    float acc = 0.f;
    for (int j = half; j < 128; j += 2)
        acc += ew[j] * t[(rbase + j) * 128 + col];
    sb[tid] = acc; __syncthreads();
    if (tid < 128) partial[blockIdx.x * 128 + tid] = sb[tid] + sb[tid + 128];
}

// ---------------- K2c: stats + sent -> ap -> LN2 -> t2 -> r = sin(t2) ----------------
__global__ __launch_bounds__(128) void k2c_finish(
    const float* __restrict__ partial, const float* __restrict__ s2,
    const float* __restrict__ anchors, const float* __restrict__ g2,
    const float* __restrict__ b2, const float* __restrict__ recvW,
    float* __restrict__ r_out)
{
    __shared__ float sent[128];
    __shared__ float na_s[128];
    __shared__ float sb[128];
    const int tid = threadIdx.x;

    float m = -1e30f;
    for (int i = tid; i < BB; i += 128) m = fmaxf(m, s2[i]);
    sb[tid] = m; __syncthreads();
    for (int s = 64; s > 0; s >>= 1) { if (tid < s) sb[tid] = fmaxf(sb[tid], sb[tid + s]); __syncthreads(); }
    m = sb[0]; __syncthreads();
    float sum = 0.f;
    for (int i = tid; i < BB; i += 128) sum += __expf(s2[i] - m);
    sb[tid] = sum; __syncthreads();
    for (int s = 64; s > 0; s >>= 1) { if (tid < s) sb[tid] += sb[tid + s]; __syncthreads(); }
    const float S = sb[0]; __syncthreads();

    float acc = 0.f;
    for (int b = 0; b < 32; ++b) acc += partial[b * 128 + tid];
    sent[tid] = acc / S;
    __syncthreads();
    float ap = 0.f;
    for (int c = 0; c < 128; ++c) ap += sent[c] * anchors[tid * 128 + c];
    sb[tid] = ap; __syncthreads();
    for (int s = 64; s > 0; s >>= 1) { if (tid < s) sb[tid] += sb[tid + s]; __syncthreads(); }
    const float mean = sb[0] * (1.0f / 128.0f); __syncthreads();
    const float dv = ap - mean;
    sb[tid] = dv * dv; __syncthreads();
    for (int s = 64; s > 0; s >>= 1) { if (tid < s) sb[tid] += sb[tid + s]; __syncthreads(); }
    const float var = sb[0] * (1.0f / 128.0f);
    const float rs = rsqrtf(var + 1e-5f);
    na_s[tid] = dv * rs * g2[tid] + b2[tid];
    __syncthreads();
    float t2 = 0.f;
    for (int k = 0; k < 128; ++k) t2 += na_s[k] * recvW[k * 128 + tid];
    r_out[tid] = sinf(t2);     // rec row == t2 row (uniform softmax over identical rows)
}

// ---------------- K3: ue = u + r (f32 + bf16 copy), pos gather ----------------
__global__ __launch_bounds__(256) void k3_ue_pos(
    const int* __restrict__ uidx, const float* __restrict__ utab,
    const int* __restrict__ pidx, const float* __restrict__ itab,
    const float* __restrict__ r, float* __restrict__ ue_out,
    float* __restrict__ pos_out, unsigned short* __restrict__ uebf)
{
    const int gid = blockIdx.x * 256 + threadIdx.x;    // 0 .. 524287
    const int i = gid >> 7, d = gid & 127;
    const float rv = r[d];
    const float u = utab[(long)uidx[i] * 128 + d];
    const float ue = u + rv;
    ue_out[gid] = ue;
    uebf[gid] = f2bf(ue);
    pos_out[gid] = itab[(long)pidx[i] * 128 + d];
}

// ---------------- K4 v13: preds = ue @ item^T  (v10 + LDS-transpose epilogue) ----------------
// v10's 256x256 / 8-wave / 0.5-ratio structure (champion, 243 us) + v4's proven
// store fix: transpose C through per-wave padded LDS slices (aliased onto the staging
// LDS after a barrier) so each store instr covers 4 rows x 256 B (4 segments) instead
// of 16 rows x 64 B (16 segments) -> 4x less TA work on the store path.
__global__ __launch_bounds__(512, 2) void k4_gemm(
    const unsigned short* __restrict__ uebf,
    const unsigned short* __restrict__ ibf,
    float* __restrict__ preds)
{
    __shared__ char smem[131072];
    unsigned short* lA = (unsigned short*)smem;            // 64 KB: 256 M-rows x 256 B
    unsigned short* lB = (unsigned short*)(smem + 65536);  // 64 KB: 256 N-cols x 256 B

    const int tid = threadIdx.x;
    const int wave = tid >> 6, lane = tid & 63;
    const int l15 = lane & 15, kg = lane >> 4;       // kg 0..3
    const int col0 = blockIdx.x * 256;               // N tile (fastest-varying)
    const int row0 = blockIdx.y * 256;               // M tile

    // ---- stage A and B (64 KB each): 8 instrs each, 8 KB per instr (512 thr x 16 B)
    #pragma unroll
    for (int i = 0; i < 8; ++i) {
        const int o  = (i * 512 + tid) * 16;
        const int r  = o >> 8;                       // tile-local row, 0..255
        const int ch = (o >> 4) & 15;
        const int sw = ch ^ (r & 15);
        gload_lds16(uebf + (size_t)(row0 + r) * 128 + sw * 8,
                    (char*)lA + i * 8192 + wave * 1024);
        const int bc = (col0 + r) < NII ? (col0 + r) : (NII - 1);
        gload_lds16(ibf + (size_t)bc * 128 + sw * 8,
                    (char*)lB + i * 8192 + wave * 1024);
    }

    const int wr = wave >> 2, wcn = wave & 3;        // 2x4 wave grid: wave tile 128M x 64N

    f4_t acc[8][4];
    #pragma unroll
    for (int m = 0; m < 8; ++m)
        #pragma unroll
        for (int n = 0; n < 4; ++n) acc[m][n] = (f4_t){0.f, 0.f, 0.f, 0.f};

    __syncthreads();

    #pragma unroll
    for (int kk = 0; kk < 4; ++kk) {                 // K step of 32
        const int c = kk * 4 + kg;
        bf8_t a[8], b[4];
        #pragma unroll
        for (int m = 0; m < 8; ++m) {
            const int r = wr * 128 + m * 16 + l15;
            a[m] = *(const bf8_t*)((const char*)lA + r * 256 + (c ^ (r & 15)) * 16);
        }
        #pragma unroll
        for (int n = 0; n < 4; ++n) {
            const int r = wcn * 64 + n * 16 + l15;
            b[n] = *(const bf8_t*)((const char*)lB + r * 256 + (c ^ (r & 15)) * 16);
        }
        #pragma unroll
        for (int m = 0; m < 8; ++m)
            #pragma unroll
            for (int n = 0; n < 4; ++n)
                acc[m][n] = __builtin_amdgcn_mfma_f32_16x16x32_bf16(b[n], a[m], acc[m][n], 0, 0, 0);
    }

    // ---- epilogue: transpose through per-wave padded LDS slice (aliases staging LDS)
    __syncthreads();                                 // all waves done reading lA/lB
    float* ep = (float*)smem + wave * (32 * 76);     // 8 waves x 9728 B = 77824 <= 128 KB

    #pragma unroll
    for (int h = 0; h < 4; ++h) {                    // four 32-row halves of 128x64 wave tile
        #pragma unroll
        for (int mm = 0; mm < 2; ++mm) {
            const int m = h * 2 + mm;
            #pragma unroll
            for (int n = 0; n < 4; ++n)
                #pragma unroll
                for (int j = 0; j < 4; ++j)
                    ep[(mm * 16 + l15) * 76 + n * 16 + kg * 4 + j] = acc[m][n][j];
        }
        // NOTE: per-wave slice -> only intra-wave ordering needed; ds ops of one wave
        // complete in order w.r.t. its own reads below (compiler inserts lgkmcnt).
        #pragma unroll
        for (int rr = 0; rr < 8; ++rr) {
            const int lrow = rr * 4 + (lane >> 4);                 // 0..31
            const f4_t v = *(const f4_t*)(ep + lrow * 76 + (lane & 15) * 4);
            const long grow = row0 + wr * 128 + h * 32 + lrow;
            const int  gcol = col0 + wcn * 64 + (lane & 15) * 4;   // 4-aligned
            if (gcol < NII)                          // NII%4==0 -> gcol<NII => gcol+3<NII
                *(fl4_t*)(preds + grow * NII + gcol) = v;
        }
    }
}

extern "C" void kernel_launch(void* const* d_in, const int* in_sizes, int n_in,
                              void* d_out, int out_size, void* d_ws, size_t ws_size,
                              hipStream_t stream) {
    const int*   uidx   = (const int*)  d_in[0];
    const int*   pidx   = (const int*)  d_in[1];
    const float* utab   = (const float*)d_in[2];
    const float* itab   = (const float*)d_in[3];
    const float* g1     = (const float*)d_in[4];
    const float* b1     = (const float*)d_in[5];
    const float* sendW  = (const float*)d_in[6];
    const float* senda  = (const float*)d_in[7];
    const float* anchors= (const float*)d_in[8];
    const float* g2     = (const float*)d_in[9];
    const float* b2     = (const float*)d_in[10];
    const float* recvW  = (const float*)d_in[11];
    // d_in[12] (recv_a) provably unused: second fca's softmax weights are exactly uniform.

    char* ws = (char*)d_ws;
    float* t_ws    = (float*)(ws + 0);              // 4096*128*4 = 2,097,152
    float* s2_ws   = (float*)(ws + 2097152);        // 16,384
    float* part_ws = (float*)(ws + 2113600);        // 32*128*4 = 16,384
    float* r_ws    = (float*)(ws + 2129984);        // 512
    unsigned short* uebf = (unsigned short*)(ws + 2130496);   // 1,048,576
    unsigned short* ibf  = (unsigned short*)(ws + 3179072);   // 12,800,000 -> ends ~15.98 MB

    float* preds   = (float*)d_out;
    float* ue_out  = preds + (long)BB * NII;
    float* pos_out = ue_out + BB * DD;

    kA_embed_cvt<<<BB + 6250, 128, 0, stream>>>(uidx, utab, g1, b1, sendW, senda,
                                                itab, t_ws, s2_ws, ibf);
    k2b_colsum<<<32, 256, 0, stream>>>(t_ws, s2_ws, part_ws);
    k2c_finish<<<1, 128, 0, stream>>>(part_ws, s2_ws, anchors, g2, b2, recvW, r_ws);
    k3_ue_pos<<<2048, 256, 0, stream>>>(uidx, utab, pidx, itab, r_ws, ue_out, pos_out, uebf);
    k4_gemm<<<dim3(196, 16, 1), 512, 0, stream>>>(uebf, ibf, preds);
}